// Round 5
// baseline (118.312 us; speedup 1.0000x reference)
//
#include <hip/hip_runtime.h>
#include <math.h>

#define B_ 2
#define T_ 16
#define N_ 128
#define CI 64
#define CO 128

// ws layout (floats), o-quad-major for coalesced consumption:
//   AQ @ 0       : 524288   AQ[b][oq32][t16][n128][4]  (a + bias)
//   BQ @ 524288  : 524288   BQ[b][oq32][t16][j128][4]  (bpart)
//   CQ @ 1048576 : 4194304  CQ[b][oq32][i128][j128][4] (cpart)
//   WT @ 5242880 : 49152    3 x [c64][oo256] effective x-weights (cls 0=t0,1=mid,2=tlast)
#define AQ_OFF 0
#define BQ_OFF 524288
#define CQ_OFF 1048576
#define WT_OFF 5242880

__device__ __forceinline__ float4 f4add(float4 a, float4 b) {
  return make_float4(a.x + b.x, a.y + b.y, a.z + b.z, a.w + b.w);
}
__device__ __forceinline__ float4 f4max(float4 a, float4 b) {
  return make_float4(fmaxf(a.x, b.x), fmaxf(a.y, b.y), fmaxf(a.z, b.z), fmaxf(a.w, b.w));
}
__device__ __forceinline__ float4 f4min(float4 a, float4 b) {
  return make_float4(fminf(a.x, b.x), fminf(a.y, b.y), fminf(a.z, b.z), fminf(a.w, b.w));
}
__device__ __forceinline__ void f4fma(float4& acc, float s, float4 v) {
  acc.x = fmaf(s, v.x, acc.x);
  acc.y = fmaf(s, v.y, acc.y);
  acc.z = fmaf(s, v.z, acc.z);
  acc.w = fmaf(s, v.w, acc.w);
}
__device__ __forceinline__ float silu1(float v) { return v / (1.0f + __expf(-v)); }
__device__ __forceinline__ float4 silu4(float4 v) {
  return make_float4(silu1(v.x), silu1(v.y), silu1(v.z), silu1(v.w));
}
__device__ __forceinline__ float4 shfl4x(float4 v, int m) {
  return make_float4(__shfl_xor(v.x, m, 64), __shfl_xor(v.y, m, 64),
                     __shfl_xor(v.z, m, 64), __shfl_xor(v.w, m, 64));
}

// =====================================================================
// k_prep: WT[cls][c][oo], oo<128 -> Weff1 col o, oo>=128 -> Weff2 col o.
// Weff = f0*W[blkA] + W[blkM] + f2*W[blkC]. 48 blocks x 256, 1 float4/thr.
// =====================================================================
__global__ __launch_bounds__(256) void k_prep(const float* __restrict__ W,
                                              float* __restrict__ WT) {
  int e4 = blockIdx.x * 256 + threadIdx.x;      // float4 index, 12288 total
  int flat = e4 * 4;
  int cls = flat / 16384;
  int rem = flat - cls * 16384;
  int c = rem >> 8;
  int oo = rem & 255;
  float f0 = (cls == 0) ? 0.0f : 1.0f;
  float f2 = (cls == 2) ? 0.0f : 1.0f;
  const float4* W4 = (const float4*)W;
  int o = oo & 127;
  int base = (oo < 128) ? 0 : 24576;            // Weff1: W rows 0..192; Weff2: 192..384
  int wi = (base + c * 128 + o) >> 2;
  float4 wa = W4[wi];
  float4 wm = W4[wi + 2048];
  float4 wc = W4[wi + 4096];
  ((float4*)WT)[e4] = make_float4(f0 * wa.x + wm.x + f2 * wc.x,
                                  f0 * wa.y + wm.y + f2 * wc.y,
                                  f0 * wa.z + wm.z + f2 * wc.z,
                                  f0 * wa.w + wm.w + f2 * wc.w);
}

// =====================================================================
// k_ab3: A/Bp GEMM from precomputed Weff (32 KB staged, was 96 KB).
// grid 512 = b(2) x t(16) x dst(2: 0->AQ,1->BQ) x nq(8, 16 rows); 256 thr.
// thread = 1 row x 2 consecutive o-quads.
// =====================================================================
__global__ __launch_bounds__(256) void k_ab3(
    const float* __restrict__ x, const float* __restrict__ WT,
    const float* __restrict__ bias, float* __restrict__ AQ, float* __restrict__ BQ)
{
  __shared__ __align__(16) float WL[64 * 128];  // [c][o], unit = c*32+u (float4)
  __shared__ float xT[64 * 17];                 // [c][n], stride 17

  int blk = blockIdx.x;
  int nq  = blk & 7;
  int dst = (blk >> 3) & 1;
  int t   = (blk >> 4) & 15;
  int b   = blk >> 8;
  int cls = (t == 0) ? 0 : ((t == T_ - 1) ? 2 : 1);
  int tid = threadIdx.x;

  const float4* WT4 = (const float4*)WT;
  float4* WL4 = (float4*)WL;
  #pragma unroll
  for (int k = 0; k < 8; k++) {
    int idx4 = tid + k * 256;                   // 2048 units = [c 64][u 32]
    WL4[idx4] = WT4[cls * 4096 + (idx4 >> 5) * 64 + dst * 32 + (idx4 & 31)];
  }
  {
    long xb = ((long)(b * T_ + t) * N_ + nq * 16) * CI;
    #pragma unroll
    for (int k = 0; k < 4; k++) {
      int idx = tid + k * 256;
      int c = idx & 63, n = idx >> 6;
      xT[c * 17 + n] = x[xb + n * CI + c];
    }
  }
  __syncthreads();

  int nl = tid & 15;
  int qg = tid >> 4;                            // 0..15 -> quads 2qg, 2qg+1
  float4 acc0, acc1;
  if (dst == 0) {
    acc0 = ((const float4*)bias)[qg * 2];
    acc1 = ((const float4*)bias)[qg * 2 + 1];
  } else {
    acc0 = make_float4(0, 0, 0, 0); acc1 = acc0;
  }
  #pragma unroll 8
  for (int c = 0; c < 64; c++) {
    float xv = xT[c * 17 + nl];
    float4 w0 = WL4[c * 32 + qg * 2];
    float4 w1 = WL4[c * 32 + qg * 2 + 1];
    f4fma(acc0, xv, w0);
    f4fma(acc1, xv, w1);
  }
  float* dp = dst ? BQ : AQ;
  int n = nq * 16 + nl;
  long u0 = ((long)(b * 32 + qg * 2) * 16 + t) * 128 + n;
  long u1 = u0 + 16 * 128;
  ((float4*)dp)[u0] = acc0;
  ((float4*)dp)[u1] = acc1;
}

// =====================================================================
// k_cp2 (unchanged from R4 — passed, conflict-free by bank arithmetic):
// CQ[b][oq][i][j] = cond[b,i,j,:]@Wc1[:,oq] + cond[b,j,i,:]@Wc2[:,oq]
// grid 1024 = b(2) x i(128) x jh(2) x of(2); 128 thr; tile 8j x 1 o-quad.
// =====================================================================
__global__ __launch_bounds__(128) void k_cp2(
    const float* __restrict__ cond, const float* __restrict__ W,
    float* __restrict__ CQ)
{
  __shared__ __align__(16) float WL[64 * 64];   // [c][o_local], unit = c*16+u
  __shared__ float Cd[64 * 65];                 // [j_local][c], stride 65

  int blk = blockIdx.x;
  int of = blk & 1;
  int jh = (blk >> 1) & 1;
  int i  = (blk >> 2) & 127;
  int b  = blk >> 9;
  int tid = threadIdx.x;
  int og = tid & 15;
  int jg = tid >> 4;                            // 0..7

  float4 acc[8];
  #pragma unroll
  for (int k = 0; k < 8; k++) acc[k] = make_float4(0, 0, 0, 0);

  const float4* W4 = (const float4*)W;
  const float4* c4p = (const float4*)cond;
  float4* WL4 = (float4*)WL;

  for (int p = 0; p < 2; p++) {
    #pragma unroll
    for (int k = 0; k < 8; k++) {
      int idx4 = tid + k * 128;                 // 1024 units = [c 64][u 16]
      int c = idx4 >> 4, u = idx4 & 15;
      WL4[idx4] = W4[(384 + p * 64 + c) * 32 + of * 16 + u];
    }
    #pragma unroll
    for (int k = 0; k < 8; k++) {
      int idx4 = tid + k * 128;                 // 1024 units = [jl 64][c4 16]
      int jl = idx4 >> 4, c4 = idx4 & 15;
      long src = (p == 0)
        ? ((long)(b * N_ + i) * N_ + jh * 64 + jl) * 16 + c4
        : ((long)(b * N_ + jh * 64 + jl) * N_ + i) * 16 + c4;
      float4 v = c4p[src];
      float* row = &Cd[jl * 65 + c4 * 4];
      row[0] = v.x; row[1] = v.y; row[2] = v.z; row[3] = v.w;
    }
    __syncthreads();
    for (int c = 0; c < 64; c++) {
      float4 w = WL4[c * 16 + og];
      #pragma unroll
      for (int k = 0; k < 8; k++) {
        float cd = Cd[(jg * 8 + k) * 65 + c];
        f4fma(acc[k], cd, w);
      }
    }
    __syncthreads();
  }
  int oq = of * 16 + og;
  long base = ((long)(b * 32 + oq) * 128 + i) * 128 + jh * 64 + jg * 8;
  float4* CQ4 = (float4*)CQ;
  #pragma unroll
  for (int k = 0; k < 8; k++) CQ4[base + k] = acc[k];
}

// =====================================================================
// k_red4: out[b,t,i,o] = max(silu(A+mx), silu(A+mn)), mx/mn = max/min_j(Bp+Cp)
// grid 512 = b(2) x oq(32) x th(2) x iq(4); 256 thr.
// ONE barrier (Bp+A staging); thread = (il 32, je 8): j's = je + 8*jj
// (interleaved: CQ loads per wave = 8 rows x 128B contiguous; BpL broadcast
// reads land on distinct bank-quads via j-stride 9 float4).
// shfl_xor(1,2,4) combines the 8 j-eighths; je==0 writes final output.
// =====================================================================
__global__ __launch_bounds__(256) void k_red4(
    const float* __restrict__ AQ, const float* __restrict__ BQ,
    const float* __restrict__ CQ, float* __restrict__ out)
{
  __shared__ __align__(16) float4 BpL4[128 * 9];  // [j][t], j-stride 9 (18.4 KB)
  __shared__ __align__(16) float4 AQL4[256];      // [t][il]                (4 KB)

  int blk = blockIdx.x;
  int iq = blk & 3;
  int th = (blk >> 2) & 1;
  int oq = (blk >> 3) & 31;
  int b  = blk >> 8;
  int tid = threadIdx.x;

  const float4* BQ4 = (const float4*)BQ;
  const float4* AQ4 = (const float4*)AQ;
  const float4* CQ4 = (const float4*)CQ;

  long slab4 = ((long)(b * 32 + oq) * 16 + th * 8) * 128;  // [t 8][j/n 128] units

  #pragma unroll
  for (int k = 0; k < 4; k++) {
    int idx = tid + k * 256;                    // [t 8][j 128]
    int t = idx >> 7, j = idx & 127;
    BpL4[j * 9 + t] = BQ4[slab4 + idx];
  }
  {
    int t = tid >> 5, il = tid & 31;
    AQL4[tid] = AQ4[slab4 + t * 128 + iq * 32 + il];
  }
  __syncthreads();

  int il = tid >> 3;                            // 0..31
  int je = tid & 7;                             // j-eighth (interleaved)

  float4 mx[8], mn[8];
  #pragma unroll
  for (int t = 0; t < 8; t++) {
    mx[t] = make_float4(-3.4e38f, -3.4e38f, -3.4e38f, -3.4e38f);
    mn[t] = make_float4(3.4e38f, 3.4e38f, 3.4e38f, 3.4e38f);
  }

  const float4* CQr = CQ4 + ((long)(b * 32 + oq) * 128 + iq * 32 + il) * 128 + je;

  #pragma unroll
  for (int jj = 0; jj < 16; jj += 4) {
    float4 c0 = CQr[(jj + 0) * 8];
    float4 c1 = CQr[(jj + 1) * 8];
    float4 c2 = CQr[(jj + 2) * 8];
    float4 c3 = CQr[(jj + 3) * 8];
    int jb0 = (je + 8 * (jj + 0)) * 9;
    int jb1 = (je + 8 * (jj + 1)) * 9;
    int jb2 = (je + 8 * (jj + 2)) * 9;
    int jb3 = (je + 8 * (jj + 3)) * 9;
    #pragma unroll
    for (int t = 0; t < 8; t++) {
      float4 s0 = f4add(c0, BpL4[jb0 + t]);
      float4 s1 = f4add(c1, BpL4[jb1 + t]);
      float4 s2 = f4add(c2, BpL4[jb2 + t]);
      float4 s3 = f4add(c3, BpL4[jb3 + t]);
      mx[t] = f4max(mx[t], f4max(f4max(s0, s1), f4max(s2, s3)));
      mn[t] = f4min(mn[t], f4min(f4min(s0, s1), f4min(s2, s3)));
    }
  }

  // combine j-eighths across lanes (je in bits 0..2 of lane id)
  #pragma unroll
  for (int t = 0; t < 8; t++) {
    mx[t] = f4max(mx[t], shfl4x(mx[t], 1));
    mn[t] = f4min(mn[t], shfl4x(mn[t], 1));
    mx[t] = f4max(mx[t], shfl4x(mx[t], 2));
    mn[t] = f4min(mn[t], shfl4x(mn[t], 2));
    mx[t] = f4max(mx[t], shfl4x(mx[t], 4));
    mn[t] = f4min(mn[t], shfl4x(mn[t], 4));
  }

  if (je == 0) {
    int i = iq * 32 + il;
    #pragma unroll
    for (int t = 0; t < 8; t++) {
      float4 av = AQL4[t * 32 + il];
      float4 M  = f4add(mx[t], av);
      float4 Mn = f4add(mn[t], av);
      float4 res = f4max(silu4(M), silu4(Mn));
      ((float4*)out)[(long)((b * 16 + th * 8 + t) * 128 + i) * 32 + oq] = res;
    }
  }
}

extern "C" void kernel_launch(void* const* d_in, const int* in_sizes, int n_in,
                              void* d_out, int out_size, void* d_ws, size_t ws_size,
                              hipStream_t stream) {
  const float* x    = (const float*)d_in[0];   // (2,16,128,64)
  const float* cond = (const float*)d_in[1];   // (2,128,128,64)
  const float* W    = (const float*)d_in[2];   // (512,128)
  const float* bias = (const float*)d_in[3];   // (128,)
  float* out = (float*)d_out;                  // (2,16,128,128)

  float* ws = (float*)d_ws;
  float* AQ = ws + AQ_OFF;
  float* BQ = ws + BQ_OFF;
  float* CQ = ws + CQ_OFF;
  float* WT = ws + WT_OFF;

  k_prep<<<48, 256, 0, stream>>>(W, WT);
  k_ab3<<<512, 256, 0, stream>>>(x, WT, bias, AQ, BQ);
  k_cp2<<<1024, 128, 0, stream>>>(cond, W, CQ);
  k_red4<<<512, 256, 0, stream>>>(AQ, BQ, CQ, out);
}

// Round 6
// 109.535 us; speedup vs baseline: 1.0801x; 1.0801x over previous
//
#include <hip/hip_runtime.h>
#include <math.h>

#define B_ 2
#define T_ 16
#define N_ 128
#define CI 64
#define CO 128

// ws layout (floats):
//   AQ @ 0       : 524288   AQ[b][oq32][t16][n128][4]  (a + bias)
//   BQ @ 524288  : 524288   BQ[b][oq32][t16][j128][4]  (bpart)
//   CQ @ 1048576 : 4194304  CQ[b][oq32][i128][j128][4] (cpart)
//   WF @ 5242880 : 8192     Wc MFMA B-fragments, 16384 bf16 (term2 x kh2 x ot8 x lane64 x u8)
#define AQ_OFF 0
#define BQ_OFF 524288
#define CQ_OFF 1048576
#define WF_OFF 5242880

typedef __attribute__((ext_vector_type(8))) short short8;
typedef __attribute__((ext_vector_type(4))) float f32x4;

__device__ __forceinline__ float4 f4add(float4 a, float4 b) {
  return make_float4(a.x + b.x, a.y + b.y, a.z + b.z, a.w + b.w);
}
__device__ __forceinline__ float4 f4max(float4 a, float4 b) {
  return make_float4(fmaxf(a.x, b.x), fmaxf(a.y, b.y), fmaxf(a.z, b.z), fmaxf(a.w, b.w));
}
__device__ __forceinline__ float4 f4min(float4 a, float4 b) {
  return make_float4(fminf(a.x, b.x), fminf(a.y, b.y), fminf(a.z, b.z), fminf(a.w, b.w));
}
__device__ __forceinline__ void f4fma(float4& acc, float s, float4 v) {
  acc.x = fmaf(s, v.x, acc.x);
  acc.y = fmaf(s, v.y, acc.y);
  acc.z = fmaf(s, v.z, acc.z);
  acc.w = fmaf(s, v.w, acc.w);
}
__device__ __forceinline__ float silu1(float v) { return v / (1.0f + __expf(-v)); }
__device__ __forceinline__ float4 silu4(float4 v) {
  return make_float4(silu1(v.x), silu1(v.y), silu1(v.z), silu1(v.w));
}
__device__ __forceinline__ float4 shfl4x(float4 v, int m) {
  return make_float4(__shfl_xor(v.x, m, 64), __shfl_xor(v.y, m, 64),
                     __shfl_xor(v.z, m, 64), __shfl_xor(v.w, m, 64));
}
// f32 -> bf16 (RNE), two floats -> packed uint32 (lo = first)
__device__ __forceinline__ unsigned int bf2(float a, float b) {
  unsigned int ua = __float_as_uint(a);
  unsigned int ub = __float_as_uint(b);
  ua = (ua + 0x7FFFu + ((ua >> 16) & 1u)) >> 16;
  ub = (ub + 0x7FFFu + ((ub >> 16) & 1u)) >> 16;
  return (ub << 16) | ua;
}
__device__ __forceinline__ uint4 pack8(float4 lo, float4 hi) {
  return make_uint4(bf2(lo.x, lo.y), bf2(lo.z, lo.w), bf2(hi.x, hi.y), bf2(hi.z, hi.w));
}

// =====================================================================
// k_prepW: pre-pack Wc1/Wc2 into MFMA B-operand fragment order (bf16).
// B-frag (16x16x32): lane holds B[k=(lane>>4)*8+u][n=lane&15].
// flat frag F = ((term*2+kh)*8+ot)*64+lane; element o = ot*16+n, k' = kh*32+k.
// grid 8 x 256, one 16B frag per thread.
// =====================================================================
__global__ __launch_bounds__(256) void k_prepW(const float* __restrict__ W,
                                               float* __restrict__ WF) {
  int fid = blockIdx.x * 256 + threadIdx.x;     // 0..2047
  int lane = fid & 63;
  int ot   = (fid >> 6) & 7;
  int kh   = (fid >> 9) & 1;
  int term = fid >> 10;
  int o  = ot * 16 + (lane & 15);
  int kb = kh * 32 + (lane >> 4) * 8;
  float v[8];
  #pragma unroll
  for (int u = 0; u < 8; u++)
    v[u] = W[(384 + term * 64 + kb + u) * 128 + o];
  uint4 pk = pack8(make_float4(v[0], v[1], v[2], v[3]),
                   make_float4(v[4], v[5], v[6], v[7]));
  ((uint4*)WF)[fid] = pk;
}

// =====================================================================
// k_ab2 (R4's known-good fused version): A/Bp from x and W directly.
// grid 512 = b(2) x t(16) x dst(2) x nq(8); 256 thr.
// =====================================================================
__global__ __launch_bounds__(256) void k_ab2(
    const float* __restrict__ x, const float* __restrict__ W,
    const float* __restrict__ bias, float* __restrict__ AQ, float* __restrict__ BQ)
{
  __shared__ __align__(16) float WL[64 * 128];  // [c][o]
  __shared__ float xT[64 * 17];                 // [c][n], stride 17

  int blk = blockIdx.x;
  int nq  = blk & 7;
  int dst = (blk >> 3) & 1;
  int t   = (blk >> 4) & 15;
  int b   = blk >> 8;
  float f0 = (t != 0)      ? 1.0f : 0.0f;
  float f2 = (t != T_ - 1) ? 1.0f : 0.0f;
  int tid = threadIdx.x;

  const float4* W4 = (const float4*)W;
  float4* WL4 = (float4*)WL;
  int wb = dst * 6144;
  #pragma unroll
  for (int k = 0; k < 8; k++) {
    int idx4 = tid + k * 256;
    float4 wa = W4[wb + idx4];
    float4 wm = W4[wb + 2048 + idx4];
    float4 wc = W4[wb + 4096 + idx4];
    WL4[idx4] = make_float4(f0 * wa.x + wm.x + f2 * wc.x,
                            f0 * wa.y + wm.y + f2 * wc.y,
                            f0 * wa.z + wm.z + f2 * wc.z,
                            f0 * wa.w + wm.w + f2 * wc.w);
  }
  {
    long xb = ((long)(b * T_ + t) * N_ + nq * 16) * CI;
    #pragma unroll
    for (int k = 0; k < 4; k++) {
      int idx = tid + k * 256;
      int c = idx & 63, n = idx >> 6;
      xT[c * 17 + n] = x[xb + n * CI + c];
    }
  }
  __syncthreads();

  int nl = tid & 15;
  int qg = tid >> 4;
  float4 acc0, acc1;
  if (dst == 0) {
    acc0 = ((const float4*)bias)[qg * 2];
    acc1 = ((const float4*)bias)[qg * 2 + 1];
  } else {
    acc0 = make_float4(0, 0, 0, 0); acc1 = acc0;
  }
  #pragma unroll 8
  for (int c = 0; c < 64; c++) {
    float xv = xT[c * 17 + nl];
    float4 w0 = WL4[c * 32 + qg * 2];
    float4 w1 = WL4[c * 32 + qg * 2 + 1];
    f4fma(acc0, xv, w0);
    f4fma(acc1, xv, w1);
  }
  float* dp = dst ? BQ : AQ;
  int n = nq * 16 + nl;
  long u0 = ((long)(b * 32 + qg * 2) * 16 + t) * 128 + n;
  long u1 = u0 + 16 * 128;
  ((float4*)dp)[u0] = acc0;
  ((float4*)dp)[u1] = acc1;
}

// =====================================================================
// k_cp3: Cp via bf16 MFMA. grid 256 = (b,i), 256 thr = 4 waves.
// D[128j][128o] = cond[b,i,:,:]@Wc1 + cond[b,:,i,:]@Wc2  (f32 acc).
// A-frags staged in frag order (conflict-free b128 reads by construction);
// Wc frags copied from precomputed WF. Wave w owns j-tiles {2w,2w+1} x 8 o-tiles
// = 64 MFMA/wave. LDS union 64 KB: AF(32K)+WF(32K) overlaid by Cp[128][128] f32.
// C/D layout (verified m89): col=lane&15, row=(lane>>4)*4+reg.
// =====================================================================
__global__ __launch_bounds__(256) void k_cp3(
    const float* __restrict__ cond, const float* __restrict__ WF,
    float* __restrict__ CQ)
{
  __shared__ __align__(16) unsigned char smem[65536];
  uint4* AF  = (uint4*)smem;             // 2048 frags: [term][jtg8][kh2][lane64]
  uint4* WcF = (uint4*)(smem + 32768);   // 2048 frags: [term][kh][ot][lane]
  float* Cp  = (float*)smem;             // overlay after MFMA: [j][o] stride 128

  int blk = blockIdx.x;
  int i = blk & 127;
  int b = blk >> 7;
  int tid = threadIdx.x;

  // ---- stage Wc fragments (straight 32 KB copy, coalesced) ----
  {
    const uint4* src = (const uint4*)WF;
    #pragma unroll
    for (int k = 0; k < 8; k++) WcF[tid + k * 256] = src[tid + k * 256];
  }
  // ---- stage A fragments for both terms ----
  #pragma unroll
  for (int term = 0; term < 2; term++) {
    #pragma unroll
    for (int k2 = 0; k2 < 4; k2++) {
      int idx = tid + k2 * 256;                 // 0..1023: j(128) x oct(8)
      int j = idx >> 3, oct = idx & 7;
      long row = (term == 0) ? ((long)(b * N_ + i) * N_ + j)
                             : ((long)(b * N_ + j) * N_ + i);
      const float4* src = (const float4*)(cond + row * 64 + oct * 8);
      float4 lo = src[0], hi = src[1];
      int frag = ((j >> 4) * 2 + (oct >> 2)) * 64 + ((oct & 3) * 16 + (j & 15));
      AF[term * 1024 + frag] = pack8(lo, hi);
    }
  }
  __syncthreads();

  // ---- MFMA ----
  int lane = tid & 63;
  int w    = tid >> 6;
  f32x4 acc[2][8];
  #pragma unroll
  for (int jt = 0; jt < 2; jt++)
    #pragma unroll
    for (int ot = 0; ot < 8; ot++) {
      acc[jt][ot][0] = 0.f; acc[jt][ot][1] = 0.f;
      acc[jt][ot][2] = 0.f; acc[jt][ot][3] = 0.f;
    }
  const short8* AF8 = (const short8*)AF;
  const short8* WF8 = (const short8*)WcF;
  #pragma unroll
  for (int term = 0; term < 2; term++) {
    #pragma unroll
    for (int kh = 0; kh < 2; kh++) {
      short8 a0 = AF8[term * 1024 + ((2 * w + 0) * 2 + kh) * 64 + lane];
      short8 a1 = AF8[term * 1024 + ((2 * w + 1) * 2 + kh) * 64 + lane];
      #pragma unroll
      for (int ot = 0; ot < 8; ot++) {
        short8 bv = WF8[((term * 2 + kh) * 8 + ot) * 64 + lane];
        acc[0][ot] = __builtin_amdgcn_mfma_f32_16x16x32_bf16(a0, bv, acc[0][ot], 0, 0, 0);
        acc[1][ot] = __builtin_amdgcn_mfma_f32_16x16x32_bf16(a1, bv, acc[1][ot], 0, 0, 0);
      }
    }
  }
  __syncthreads();   // frag reads done; safe to overlay Cp

  // ---- epilogue: acc -> Cp[j][o] (stride 128) ----
  {
    int col = lane & 15;
    int rsub = (lane >> 4) * 4;
    #pragma unroll
    for (int jt = 0; jt < 2; jt++) {
      int row0 = (2 * w + jt) * 16 + rsub;
      #pragma unroll
      for (int ot = 0; ot < 8; ot++) {
        f32x4 d = acc[jt][ot];
        int cbase = ot * 16 + col;
        Cp[(row0 + 0) * 128 + cbase] = d[0];
        Cp[(row0 + 1) * 128 + cbase] = d[1];
        Cp[(row0 + 2) * 128 + cbase] = d[2];
        Cp[(row0 + 3) * 128 + cbase] = d[3];
      }
    }
  }
  __syncthreads();

  // ---- store CQ[b][oq][i][j] quad-major ----
  {
    const float4* Cp4 = (const float4*)Cp;
    float4* CQ4 = (float4*)CQ;
    #pragma unroll
    for (int it = 0; it < 16; it++) {
      int idx = tid + it * 256;                 // 4096 = oq(32) x j(128)
      int oq = idx & 31, j = idx >> 5;
      CQ4[((long)(b * 32 + oq) * 128 + i) * 128 + j] = Cp4[j * 32 + oq];
    }
  }
}

// =====================================================================
// k_red4 (unchanged): out = max(silu(A+mx), silu(A+mn)), mx/mn over j.
// grid 512 = b(2) x oq(32) x th(2) x iq(4); 256 thr; ONE barrier.
// =====================================================================
__global__ __launch_bounds__(256) void k_red4(
    const float* __restrict__ AQ, const float* __restrict__ BQ,
    const float* __restrict__ CQ, float* __restrict__ out)
{
  __shared__ __align__(16) float4 BpL4[128 * 9];
  __shared__ __align__(16) float4 AQL4[256];

  int blk = blockIdx.x;
  int iq = blk & 3;
  int th = (blk >> 2) & 1;
  int oq = (blk >> 3) & 31;
  int b  = blk >> 8;
  int tid = threadIdx.x;

  const float4* BQ4 = (const float4*)BQ;
  const float4* AQ4 = (const float4*)AQ;
  const float4* CQ4 = (const float4*)CQ;

  long slab4 = ((long)(b * 32 + oq) * 16 + th * 8) * 128;

  #pragma unroll
  for (int k = 0; k < 4; k++) {
    int idx = tid + k * 256;
    int t = idx >> 7, j = idx & 127;
    BpL4[j * 9 + t] = BQ4[slab4 + idx];
  }
  {
    int t = tid >> 5, il = tid & 31;
    AQL4[tid] = AQ4[slab4 + t * 128 + iq * 32 + il];
  }
  __syncthreads();

  int il = tid >> 3;
  int je = tid & 7;

  float4 mx[8], mn[8];
  #pragma unroll
  for (int t = 0; t < 8; t++) {
    mx[t] = make_float4(-3.4e38f, -3.4e38f, -3.4e38f, -3.4e38f);
    mn[t] = make_float4(3.4e38f, 3.4e38f, 3.4e38f, 3.4e38f);
  }

  const float4* CQr = CQ4 + ((long)(b * 32 + oq) * 128 + iq * 32 + il) * 128 + je;

  #pragma unroll
  for (int jj = 0; jj < 16; jj += 4) {
    float4 c0 = CQr[(jj + 0) * 8];
    float4 c1 = CQr[(jj + 1) * 8];
    float4 c2 = CQr[(jj + 2) * 8];
    float4 c3 = CQr[(jj + 3) * 8];
    int jb0 = (je + 8 * (jj + 0)) * 9;
    int jb1 = (je + 8 * (jj + 1)) * 9;
    int jb2 = (je + 8 * (jj + 2)) * 9;
    int jb3 = (je + 8 * (jj + 3)) * 9;
    #pragma unroll
    for (int t = 0; t < 8; t++) {
      float4 s0 = f4add(c0, BpL4[jb0 + t]);
      float4 s1 = f4add(c1, BpL4[jb1 + t]);
      float4 s2 = f4add(c2, BpL4[jb2 + t]);
      float4 s3 = f4add(c3, BpL4[jb3 + t]);
      mx[t] = f4max(mx[t], f4max(f4max(s0, s1), f4max(s2, s3)));
      mn[t] = f4min(mn[t], f4min(f4min(s0, s1), f4min(s2, s3)));
    }
  }

  #pragma unroll
  for (int t = 0; t < 8; t++) {
    mx[t] = f4max(mx[t], shfl4x(mx[t], 1));
    mn[t] = f4min(mn[t], shfl4x(mn[t], 1));
    mx[t] = f4max(mx[t], shfl4x(mx[t], 2));
    mn[t] = f4min(mn[t], shfl4x(mn[t], 2));
    mx[t] = f4max(mx[t], shfl4x(mx[t], 4));
    mn[t] = f4min(mn[t], shfl4x(mn[t], 4));
  }

  if (je == 0) {
    int i = iq * 32 + il;
    #pragma unroll
    for (int t = 0; t < 8; t++) {
      float4 av = AQL4[t * 32 + il];
      float4 M  = f4add(mx[t], av);
      float4 Mn = f4add(mn[t], av);
      float4 res = f4max(silu4(M), silu4(Mn));
      ((float4*)out)[(long)((b * 16 + th * 8 + t) * 128 + i) * 32 + oq] = res;
    }
  }
}

extern "C" void kernel_launch(void* const* d_in, const int* in_sizes, int n_in,
                              void* d_out, int out_size, void* d_ws, size_t ws_size,
                              hipStream_t stream) {
  const float* x    = (const float*)d_in[0];   // (2,16,128,64)
  const float* cond = (const float*)d_in[1];   // (2,128,128,64)
  const float* W    = (const float*)d_in[2];   // (512,128)
  const float* bias = (const float*)d_in[3];   // (128,)
  float* out = (float*)d_out;                  // (2,16,128,128)

  float* ws = (float*)d_ws;
  float* AQ = ws + AQ_OFF;
  float* BQ = ws + BQ_OFF;
  float* CQ = ws + CQ_OFF;
  float* WF = ws + WF_OFF;

  k_prepW<<<8, 256, 0, stream>>>(W, WF);
  k_ab2<<<512, 256, 0, stream>>>(x, W, bias, AQ, BQ);
  k_cp3<<<256, 256, 0, stream>>>(cond, WF, CQ);
  k_red4<<<512, 256, 0, stream>>>(AQ, BQ, CQ, out);
}